// Round 4
// baseline (44.559 us; speedup 1.0000x reference)
//
#include <hip/hip_runtime.h>
#include <hip/hip_cooperative_groups.h>

namespace cg = cooperative_groups;

#define NATOMS 4096
#define MAXP   32768
#define CUTOFF 5.0f
#define OUT_TOTAL (6 * MAXP)   // 65536 neighbors + 32768 dist + 98304 vecs
#define NBLK   256
#define TPB    1024
#define WPB    16              // waves (= rows) per block
#define CCH    4               // register-cached 64-wide chunks per row

// Uniform helper: first index > i where batch[] != b (batch is sorted).
__device__ __forceinline__ int row_end(const int* __restrict__ batch, int i, int b) {
    int lo = i + 1, hi = NATOMS;
    while (lo < hi) {
        int mid = (lo + hi) >> 1;
        if (batch[mid] == b) lo = mid + 1; else hi = mid;
    }
    return lo;
}

__global__ __launch_bounds__(TPB, 1)
void fused_k(const float* __restrict__ pos,
             const int*   __restrict__ batch,
             int*         __restrict__ bsum,
             float*       __restrict__ out) {
#pragma clang fp contract(off)
    const int tid = threadIdx.x;
    const int p   = blockIdx.x;

    // --- fill slice: 256 blocks * 1024 threads = 262144 >= 196608 ---
    {
        int idx = p * TPB + tid;
        if (idx < OUT_TOTAL) out[idx] = (idx < 2 * MAXP) ? -1.0f : 0.0f;
    }

    const int w    = tid >> 6;
    const int lane = tid & 63;
    const int i    = p * WPB + w;          // row owned by this wave

    const int b   = batch[i];
    const int end = row_end(batch, i, b);
    const float xi = pos[3 * i + 0];
    const float yi = pos[3 * i + 1];
    const float zi = pos[3 * i + 2];

    // ---- Phase A: compute validity/distances, cache in registers ----
    float cd[CCH], cvx[CCH], cvy[CCH], cvz[CCH];
    int   crank[CCH];                      // rank within row, or -1 if invalid
    int   c = 0;                           // running row pair count
#pragma unroll
    for (int k = 0; k < CCH; ++k) {
        crank[k] = -1; cd[k] = 0.f; cvx[k] = 0.f; cvy[k] = 0.f; cvz[k] = 0.f;
        int j0 = i + 1 + k * 64;
        if (j0 < end) {
            int j = j0 + lane;
            bool valid = false;
            float vx = 0.f, vy = 0.f, vz = 0.f, d = 0.f;
            if (j < end) {
                vx = xi - pos[3 * j + 0];
                vy = yi - pos[3 * j + 1];
                vz = zi - pos[3 * j + 2];
                float d2 = vx * vx + vy * vy + vz * vz;
                d = sqrtf(d2);
                valid = d < CUTOFF;
            }
            unsigned long long m = __ballot(valid);
            if (valid) {
                crank[k] = c + __popcll(m & ((1ULL << lane) - 1ULL));
                cd[k] = d; cvx[k] = vx; cvy[k] = vy; cvz[k] = vz;
            }
            c += __popcll(m);
        }
    }
    const int c_cached = c;
    // tail chunks beyond the register cache (fallback, not expected here)
    for (int j0 = i + 1 + CCH * 64; j0 < end; j0 += 64) {
        int j = j0 + lane;
        bool valid = false;
        if (j < end) {
            float vx = xi - pos[3 * j + 0];
            float vy = yi - pos[3 * j + 1];
            float vz = zi - pos[3 * j + 2];
            valid = sqrtf(vx * vx + vy * vy + vz * vz) < CUTOFF;
        }
        c += __popcll(__ballot(valid));
    }

    __shared__ int ls[WPB];
    __shared__ int pfx;
    if (lane == 0) ls[w] = c;
    __syncthreads();
    if (tid == 0) {
        int s = 0;
        for (int k = 0; k < WPB; ++k) s += ls[k];
        bsum[p] = s;
    }

    cg::this_grid().sync();

    // ---- Phase B: global prefix for this block, then direct writes ----
    if (w == 0) {
        int s = 0;
        for (int q = lane; q < p; q += 64) s += bsum[q];
        for (int o = 32; o; o >>= 1) s += __shfl_down(s, o);
        if (lane == 0) pfx = s;
    }
    __syncthreads();

    int rowbase = pfx;
    for (int r = 0; r < w; ++r) rowbase += ls[r];

#pragma unroll
    for (int k = 0; k < CCH; ++k) {
        if (crank[k] >= 0) {
            int slot = rowbase + crank[k];
            if (slot < MAXP) {
                int j = i + 1 + k * 64 + lane;
                out[slot]            = (float)i;   // neighbors[0, slot]
                out[MAXP + slot]     = (float)j;   // neighbors[1, slot]
                out[2 * MAXP + slot] = cd[k];      // distances[slot]
                float* v = out + 3 * MAXP + 3 * slot;
                v[0] = cvx[k]; v[1] = cvy[k]; v[2] = cvz[k];
            }
        }
    }
    // tail chunks: recompute (identical arithmetic -> identical mask/order)
    int slotbase = rowbase + c_cached;
    for (int j0 = i + 1 + CCH * 64; j0 < end; j0 += 64) {
        int j = j0 + lane;
        bool valid = false;
        float vx = 0.f, vy = 0.f, vz = 0.f, d = 0.f;
        if (j < end) {
            vx = xi - pos[3 * j + 0];
            vy = yi - pos[3 * j + 1];
            vz = zi - pos[3 * j + 2];
            float d2 = vx * vx + vy * vy + vz * vz;
            d = sqrtf(d2);
            valid = d < CUTOFF;
        }
        unsigned long long m = __ballot(valid);
        if (valid) {
            int slot = slotbase + __popcll(m & ((1ULL << lane) - 1ULL));
            if (slot < MAXP) {
                out[slot]            = (float)i;
                out[MAXP + slot]     = (float)j;
                out[2 * MAXP + slot] = d;
                float* v = out + 3 * MAXP + 3 * slot;
                v[0] = vx; v[1] = vy; v[2] = vz;
            }
        }
        slotbase += __popcll(m);
    }
}

extern "C" void kernel_launch(void* const* d_in, const int* in_sizes, int n_in,
                              void* d_out, int out_size, void* d_ws, size_t ws_size,
                              hipStream_t stream) {
    const float* pos   = (const float*)d_in[0];   // [4096,3] f32
    const int*   batch = (const int*)d_in[1];     // [4096] i32 (sorted)
    float* out = (float*)d_out;                   // 196608 f32 (all outputs)
    int*   bsum = (int*)d_ws;                     // 256 ints

    void* args[] = { (void*)&pos, (void*)&batch, (void*)&bsum, (void*)&out };
    hipLaunchCooperativeKernel((void*)fused_k, dim3(NBLK), dim3(TPB),
                               args, 0, stream);
}

// Round 5
// 14.574 us; speedup vs baseline: 3.0574x; 3.0574x over previous
//
#include <hip/hip_runtime.h>

#define NATOMS 4096
#define MAXP   32768
#define CUTOFF 5.0f
#define OUT_TOTAL (6 * MAXP)   // 65536 neighbors + 32768 dist + 98304 vecs
#define NBLK   1024            // 4 rows per block
#define TPB    256
#define WPB    4               // waves (= rows) per block
#define PSTRIDE 256            // cached pairs per row in ws
#define PFLOATS (PSTRIDE * 5)  // j,d,vx,vy,vz per pair

// ---------------------------------------------------------------------------
// K1: output init + per-row count + compacted pair cache into ws.
// One wave per row; molecule boundary detected inline via ballot (batch sorted).
// ---------------------------------------------------------------------------
__global__ void count_k(const float* __restrict__ pos,
                        const int*   __restrict__ batch,
                        int*         __restrict__ cnt,
                        int*         __restrict__ bsum,
                        float*       __restrict__ pair,
                        float*       __restrict__ out) {
#pragma clang fp contract(off)
    const int tid = threadIdx.x;
    const int p   = blockIdx.x;

    // --- fill slice: 1024 blocks * 256 threads = 262144 >= 196608 ---
    {
        int idx = p * TPB + tid;
        if (idx < OUT_TOTAL) out[idx] = (idx < 2 * MAXP) ? -1.0f : 0.0f;
    }

    const int w    = tid >> 6;
    const int lane = tid & 63;
    const int i    = p * WPB + w;

    const int b = batch[i];
    const float xi = pos[3 * i + 0];
    const float yi = pos[3 * i + 1];
    const float zi = pos[3 * i + 2];
    float* rowp = pair + (size_t)i * PFLOATS;

    int c = 0;
    for (int j0 = i + 1; j0 < NATOMS; j0 += 64) {
        int j = j0 + lane;
        bool in = j < NATOMS;
        int bj = in ? batch[j] : -1;
        bool same = in && (bj == b);
        float vx = 0.f, vy = 0.f, vz = 0.f, d = 0.f;
        bool valid = false;
        if (same) {
            vx = xi - pos[3 * j + 0];
            vy = yi - pos[3 * j + 1];
            vz = zi - pos[3 * j + 2];
            float d2 = vx * vx + vy * vy + vz * vz;
            d = sqrtf(d2);
            valid = d < CUTOFF;
        }
        unsigned long long m = __ballot(valid);
        if (valid) {
            int r = c + __popcll(m & ((1ULL << lane) - 1ULL));
            if (r < PSTRIDE) {
                float* q = rowp + r * 5;
                q[0] = (float)j; q[1] = d; q[2] = vx; q[3] = vy; q[4] = vz;
            }
        }
        c += __popcll(m);
        // row ends inside this chunk if any in-range lane left the molecule
        if (__any(in && (bj != b))) break;
    }

    __shared__ int ls[WPB];
    if (lane == 0) { cnt[i] = c; ls[w] = c; }
    __syncthreads();
    if (tid == 0) bsum[p] = ls[0] + ls[1] + ls[2] + ls[3];
}

// ---------------------------------------------------------------------------
// K2: per-block global prefix (wave 0, shfl reduce) + copy cached pairs to
// their final slots. Fallback recompute only if a row overflowed PSTRIDE.
// ---------------------------------------------------------------------------
__global__ void write_k(const float* __restrict__ pos,
                        const int*   __restrict__ batch,
                        const int*   __restrict__ cnt,
                        const int*   __restrict__ bsum,
                        const float* __restrict__ pair,
                        float*       __restrict__ out) {
#pragma clang fp contract(off)
    const int tid  = threadIdx.x;
    const int p    = blockIdx.x;
    const int w    = tid >> 6;
    const int lane = tid & 63;
    const int i    = p * WPB + w;

    __shared__ int ls[WPB];
    __shared__ int pfx;

    const int c = cnt[i];
    if (lane == 0) ls[w] = c;

    if (w == 0) {
        int s = 0;
        for (int q = lane; q < p; q += 64) s += bsum[q];
        for (int o = 32; o; o >>= 1) s += __shfl_down(s, o);
        if (lane == 0) pfx = s;
    }
    __syncthreads();

    int rowbase = pfx;
    for (int r = 0; r < w; ++r) rowbase += ls[r];

    if (c <= PSTRIDE) {
        const float* rowp = pair + (size_t)i * PFLOATS;
        for (int t = lane; t < c; t += 64) {
            int slot = rowbase + t;
            if (slot < MAXP) {
                const float* q = rowp + t * 5;
                out[slot]            = (float)i;  // neighbors[0, slot]
                out[MAXP + slot]     = q[0];      // neighbors[1, slot] (= j)
                out[2 * MAXP + slot] = q[1];      // distances[slot]
                float* v = out + 3 * MAXP + 3 * slot;
                v[0] = q[2]; v[1] = q[3]; v[2] = q[4];
            }
        }
    } else {
        // pathological row: recompute with identical arithmetic/order
        const int b = batch[i];
        const float xi = pos[3 * i + 0];
        const float yi = pos[3 * i + 1];
        const float zi = pos[3 * i + 2];
        int slotbase = rowbase;
        for (int j0 = i + 1; j0 < NATOMS; j0 += 64) {
            int j = j0 + lane;
            bool in = j < NATOMS;
            int bj = in ? batch[j] : -1;
            bool same = in && (bj == b);
            float vx = 0.f, vy = 0.f, vz = 0.f, d = 0.f;
            bool valid = false;
            if (same) {
                vx = xi - pos[3 * j + 0];
                vy = yi - pos[3 * j + 1];
                vz = zi - pos[3 * j + 2];
                float d2 = vx * vx + vy * vy + vz * vz;
                d = sqrtf(d2);
                valid = d < CUTOFF;
            }
            unsigned long long m = __ballot(valid);
            if (valid) {
                int slot = slotbase + __popcll(m & ((1ULL << lane) - 1ULL));
                if (slot < MAXP) {
                    out[slot]            = (float)i;
                    out[MAXP + slot]     = (float)j;
                    out[2 * MAXP + slot] = d;
                    float* v = out + 3 * MAXP + 3 * slot;
                    v[0] = vx; v[1] = vy; v[2] = vz;
                }
            }
            slotbase += __popcll(m);
            if (__any(in && (bj != b))) break;
        }
    }
}

extern "C" void kernel_launch(void* const* d_in, const int* in_sizes, int n_in,
                              void* d_out, int out_size, void* d_ws, size_t ws_size,
                              hipStream_t stream) {
    const float* pos   = (const float*)d_in[0];   // [4096,3] f32
    const int*   batch = (const int*)d_in[1];     // [4096] i32 (sorted)
    float* out = (float*)d_out;                   // 196608 f32 (all outputs)

    int*   cnt  = (int*)d_ws;                 // 4096 ints
    int*   bsum = cnt + NATOMS;               // 1024 ints
    float* pair = (float*)(bsum + NBLK);      // 4096 * 1280 floats (~21 MB)

    count_k<<<NBLK, TPB, 0, stream>>>(pos, batch, cnt, bsum, pair, out);
    write_k<<<NBLK, TPB, 0, stream>>>(pos, batch, cnt, bsum, pair, out);
}